// Round 6
// baseline (207.978 us; speedup 1.0000x reference)
//
#include <hip/hip_runtime.h>
#include <math.h>

// Problem constants (from reference)
#define Bb   8
#define Qq   64
#define Kk   256
#define Dd   256
#define Nn   (Bb * Qq)          // 512
#define GNi  0.0625f            // 1/GN
#define EPSf 1e-5f
#define WB   1088               // packed width: q(256)|k(256)|v(256)|pre(256)|r(4)|pad(60)

// ---------------------------------------------------------------------------
// 64-lane wave reduction (sum), result broadcast to all lanes
__device__ __forceinline__ float wred(float x) {
#pragma unroll
    for (int off = 32; off > 0; off >>= 1)
        x += __shfl_xor(x, off, 64);
    return x;
}

// ---------------------------------------------------------------------------
// Pack Wb (256 x 1088) = [W_q | W_k | W_v | W_gk1@W_gk2 | W_router | 0-pad]
__global__ __launch_bounds__(256) void pack_wb(
    const float* __restrict__ Wq, const float* __restrict__ Wk,
    const float* __restrict__ Wv, const float* __restrict__ Wg1,
    const float* __restrict__ Wg2, const float* __restrict__ Wr,
    float* __restrict__ Wb)
{
    const int idx = blockIdx.x * 256 + threadIdx.x;   // < 256*1088
    const int k = idx / WB, j = idx % WB;
    float v;
    if (j < 256)       v = Wq[(size_t)k * 256 + j];
    else if (j < 512)  v = Wk[(size_t)k * 256 + j - 256];
    else if (j < 768)  v = Wv[(size_t)k * 256 + j - 512];
    else if (j < 1024) {
        const int c = j - 768;
        float s = 0.f;
#pragma unroll
        for (int i = 0; i < 16; ++i)
            s = fmaf(Wg1[(size_t)k * 16 + i], Wg2[(size_t)i * 256 + c], s);
        v = s;                                   // Wg = W_gk1 @ W_gk2
    }
    else if (j < 1028) v = Wr[(size_t)k * 4 + (j - 1024)];
    else               v = 0.f;
    Wb[idx] = v;
}

// ---------------------------------------------------------------------------
// GEMM core: 128x64 tile, K=256, 8x4 microtile, 256 threads.
// A row-major lda=256; Bm column-window (64 cols), leading dim ldb.
// As stored k-major [16][132] (b128-aligned, broadcast reads);
// Ws [16][68] (2-way = free).
__device__ __forceinline__ void gemm_core(
    const float* __restrict__ A, const float* __restrict__ Bm, int ldb,
    float (&acc)[8][4], float* As, float* Ws)
{
    const int tid = threadIdx.x;
    const int r  = tid >> 1;            // 0..127 A-load row
    const int kl = (tid & 1) * 8;       // 0 or 8
    const int wc = tid & 63;            // B-load col
    const int kr = (tid >> 6) * 4;      // B-load row group
    const int ty = tid >> 4;            // rows ty*8..+7
    const int tx = tid & 15;            // cols tx*4..+3

    for (int k0 = 0; k0 < Dd; k0 += 16) {
        const float4 a0 = *(const float4*)(A + (size_t)r * Dd + k0 + kl);
        const float4 a1 = *(const float4*)(A + (size_t)r * Dd + k0 + kl + 4);
        As[(kl + 0) * 132 + r] = a0.x;
        As[(kl + 1) * 132 + r] = a0.y;
        As[(kl + 2) * 132 + r] = a0.z;
        As[(kl + 3) * 132 + r] = a0.w;
        As[(kl + 4) * 132 + r] = a1.x;
        As[(kl + 5) * 132 + r] = a1.y;
        As[(kl + 6) * 132 + r] = a1.z;
        As[(kl + 7) * 132 + r] = a1.w;
#pragma unroll
        for (int u = 0; u < 4; ++u)
            Ws[(kr + u) * 68 + wc] = Bm[(size_t)(k0 + kr + u) * ldb + wc];
        __syncthreads();
#pragma unroll
        for (int kk = 0; kk < 16; ++kk) {
            const float4 aL = *(const float4*)&As[kk * 132 + ty * 8];
            const float4 aH = *(const float4*)&As[kk * 132 + ty * 8 + 4];
            const float4 bv = *(const float4*)&Ws[kk * 68 + tx * 4];
            const float av[8] = {aL.x, aL.y, aL.z, aL.w, aH.x, aH.y, aH.z, aH.w};
            const float bw[4] = {bv.x, bv.y, bv.z, bv.w};
#pragma unroll
            for (int i = 0; i < 8; ++i)
#pragma unroll
                for (int j = 0; j < 4; ++j)
                    acc[i][j] = fmaf(av[i], bw[j], acc[i][j]);
        }
        __syncthreads();
    }
}

// ---------------------------------------------------------------------------
// gemm1: 225 blocks.
//  id <208 : KVi = keyval @ Wb[:,256:1088]  (2048 x 832), interleaved store
//            KVi[row][c] = {k,v,pre,pad}; router cols -> KVr[row][4].
//  id <224 : cond = query @ W_cond  (512 x 256), plain float4 store.
//  id ==224: KVq8[b][c] = keyval[b,255,:] @ W_q  (uses Wb q-region).
__global__ __launch_bounds__(256) void gemm1(
    const float* __restrict__ keyval, const float* __restrict__ query,
    const float* __restrict__ Wb, const float* __restrict__ W_cond,
    float* __restrict__ KVi, float* __restrict__ KVr,
    float* __restrict__ cond, float* __restrict__ KVq8)
{
    __shared__ float As[16 * 132];
    __shared__ float Ws[16 * 68];
    const int id = blockIdx.x;
    const int tid = threadIdx.x;

    if (id == 224) {   // KVq8 micro-block
        for (int b8 = 0; b8 < 8; ++b8)
            As[b8 * 256 + tid] = keyval[((size_t)b8 * Kk + 255) * Dd + tid];
        __syncthreads();
        float acc8[8] = {};
        for (int k = 0; k < 256; ++k) {
            const float wq = Wb[(size_t)k * WB + tid];   // q region, col tid
#pragma unroll
            for (int b8 = 0; b8 < 8; ++b8)
                acc8[b8] = fmaf(As[b8 * 256 + k], wq, acc8[b8]);
        }
        for (int b8 = 0; b8 < 8; ++b8)
            KVq8[b8 * 256 + tid] = acc8[b8];
        return;
    }

    float acc[8][4] = {};
    const int ty = tid >> 4, tx = tid & 15;

    if (id < 208) {
        const int bm  = (id / 13) * 128;
        const int bnA = 256 + (id % 13) * 64;     // absolute Wb col
        gemm_core(keyval + (size_t)bm * Dd, Wb + bnA, WB, acc, As, Ws);
        if (bnA < 1024) {
            const int reg = (bnA >> 8) - 1;       // 0=k,1=v,2=pre
            const int cb  = bnA & 255;
#pragma unroll
            for (int i = 0; i < 8; ++i) {
                const size_t rowo = (size_t)(bm + ty * 8 + i) * 1024;
#pragma unroll
                for (int jj = 0; jj < 4; ++jj)
                    KVi[rowo + (size_t)(cb + tx * 4 + jj) * 4 + reg] = acc[i][jj];
            }
        } else if (tx == 0) {                     // router cols 1024..1027
#pragma unroll
            for (int i = 0; i < 8; ++i)
                *(float4*)&KVr[(size_t)(bm + ty * 8 + i) * 4] =
                    make_float4(acc[i][0], acc[i][1], acc[i][2], acc[i][3]);
        }
    } else {
        const int id2 = id - 208;
        const int bm = (id2 >> 2) * 128;
        const int bn = (id2 & 3) * 64;
        gemm_core(query + (size_t)bm * Dd, W_cond + bn, Dd, acc, As, Ws);
#pragma unroll
        for (int i = 0; i < 8; ++i)
            *(float4*)&cond[(size_t)(bm + ty * 8 + i) * Dd + bn + tx * 4] =
                make_float4(acc[i][0], acc[i][1], acc[i][2], acc[i][3]);
    }
}

// ---------------------------------------------------------------------------
// gemm2: Cbi = cond @ Wb (512 x 1088), interleaved {q,k,v,pre}; router -> Cr.
__global__ __launch_bounds__(256) void gemm2(
    const float* __restrict__ cond, const float* __restrict__ Wb,
    float* __restrict__ Cbi, float* __restrict__ Cr)
{
    __shared__ float As[16 * 132];
    __shared__ float Ws[16 * 68];
    const int id = blockIdx.x;
    const int tid = threadIdx.x;
    const int bm = (id / 17) * 128;
    const int bn = (id % 17) * 64;
    float acc[8][4] = {};
    gemm_core(cond + (size_t)bm * Dd, Wb + bn, WB, acc, As, Ws);
    const int ty = tid >> 4, tx = tid & 15;
    if (bn < 1024) {
        const int reg = bn >> 8;                  // 0=q,1=k,2=v,3=pre
        const int cb  = bn & 255;
#pragma unroll
        for (int i = 0; i < 8; ++i) {
            const size_t rowo = (size_t)(bm + ty * 8 + i) * 1024;
#pragma unroll
            for (int jj = 0; jj < 4; ++jj)
                Cbi[rowo + (size_t)(cb + tx * 4 + jj) * 4 + reg] = acc[i][jj];
        }
    } else if (tx == 0) {
#pragma unroll
        for (int i = 0; i < 8; ++i)
            *(float4*)&Cr[(size_t)(bm + ty * 8 + i) * 4] =
                make_float4(acc[i][0], acc[i][1], acc[i][2], acc[i][3]);
    }
}

// ---------------------------------------------------------------------------
// One 16-t tile of the reverse recurrence: phase A from registers (buf),
// phase B wave-local LDS transpose-reduce.
__device__ __forceinline__ void tile_step(
    const float4* buf, int t0, const int* __restrict__ pm, const float4* wm,
    float ql, float kc, float vc, float pc,
    float& E0, float& E1, float& E2, float& E3, float& E4, float& o,
    float (*Pt)[68], float* sb, int lane, int tl, int qq)
{
    float vreg[16];
#pragma unroll
    for (int i = 0; i < 16; ++i) {
        const int t = t0 + 15 - i;
        const float mf = (float)pm[t];
        const float4 kv = buf[i];
        const float kkv = (kv.x + kc) * mf;
        vreg[i] = (kv.y + vc) * mf;
        const float pre = kv.z + pc;
        const float4 w = wm[t];
        const float ls = fminf(pre, 0.f) - __logf(1.f + __expf(-fabsf(pre)));
        float dg = __expf(ls * GNi);
        dg = (mf != 0.f) ? dg : 1.f;
        const float zf = E0 + w.x * E1 + w.y * E2 + w.z * E3 + w.w * E4;
        Pt[i][lane] = ql * kkv * zf;
        E0 *= dg;
        E1 *= (w.x > 0.f) ? dg : 1.f;
        E2 *= (w.y > 0.f) ? dg : 1.f;
        E3 *= (w.z > 0.f) ? dg : 1.f;
        E4 *= (w.w > 0.f) ? dg : 1.f;
    }
    __builtin_amdgcn_wave_barrier();
    float s = 0.f;
#pragma unroll
    for (int r = 0; r < 4; ++r) {
        const float4 p4 = *(const float4*)&Pt[tl][qq * 16 + r * 4];
        s += (p4.x + p4.y) + (p4.z + p4.w);
    }
    s += __shfl_xor(s, 16, 64);
    s += __shfl_xor(s, 32, 64);
    sb[tl] = s;                       // same-value multi-write, benign
    __builtin_amdgcn_wave_barrier();
#pragma unroll
    for (int r = 0; r < 4; ++r) {
        const float4 sv = *(const float4*)&sb[r * 4];
        o = fmaf(sv.x, vreg[r * 4 + 0], o);
        o = fmaf(sv.y, vreg[r * 4 + 1], o);
        o = fmaf(sv.z, vreg[r * 4 + 2], o);
        o = fmaf(sv.w, vreg[r * 4 + 3], o);
    }
}

// ---------------------------------------------------------------------------
// Fused router + recurrence + RMSNorm + W_o projection. One block per n.
// Double-buffered register prefetch of the interleaved KVi stream.
__global__ __launch_bounds__(256, 2) void mom_fused(
    const float4* __restrict__ KVi, const float* __restrict__ KVr,
    const float4* __restrict__ Cbi, const float* __restrict__ Cr,
    const float* __restrict__ KVq8, const float* __restrict__ b_gk2,
    const int* __restrict__ mask, const float* __restrict__ W_o,
    const float* __restrict__ norm_w,
    float* __restrict__ out, float* __restrict__ logits)
{
    __shared__ float4 wm[Kk];
    __shared__ float  Ptile[4][16][68];
    __shared__ float  sbuf[4][16];
    __shared__ float  onorm[Dd];

    const int n = blockIdx.x;
    const int b = n >> 6;
    const int j = threadIdx.x;
    const int lane = j & 63;
    const int wv = j >> 6;

    // cond-side values (interleaved)
    const float4 c4 = Cbi[(size_t)n * 256 + j];
    const float qc = c4.x, kc = c4.y, vc = c4.z;
    const float pc = c4.w + b_gk2[j];
    const float ql = KVq8[b * 256 + j] + qc;

    // ---- router top-2 for t = j
    {
        const float4 kvr = *(const float4*)&KVr[(size_t)(b * Kk + j) * 4];
        const float4 cr  = *(const float4*)&Cr[(size_t)n * 4];
        float l[4] = {kvr.x + cr.x, kvr.y + cr.y, kvr.z + cr.z, kvr.w + cr.w};
        *(float4*)(logits + ((size_t)n * Kk + j) * 4) =
            make_float4(l[0], l[1], l[2], l[3]);

        int i1 = 0;
#pragma unroll
        for (int q = 1; q < 4; ++q) if (l[q] > l[i1]) i1 = q;
        int i2 = -1;
#pragma unroll
        for (int q = 0; q < 4; ++q) {
            if (q == i1) continue;
            if (i2 < 0 || l[q] > l[i2]) i2 = q;
        }
        const float mx = fmaxf(l[i1], l[i2]);
        const float e1 = __expf(l[i1] - mx);
        const float e2 = __expf(l[i2] - mx);
        const float inv = 1.f / (e1 + e2);
        float w[4] = {0.f, 0.f, 0.f, 0.f};
        w[i1] = e1 * inv;
        w[i2] = e2 * inv;
        wm[j] = make_float4(w[0], w[1], w[2], w[3]);
    }
    __syncthreads();

    const float4* pkv = KVi + (size_t)b * Kk * 256 + j;
    const int*    pm  = mask + b * Kk;

    float E0 = 1.f, E1 = 1.f, E2 = 1.f, E3 = 1.f, E4 = 1.f;
    float o = 0.f;
    const int tl = lane & 15, qq = lane >> 4;

    float4 bufA[16], bufB[16];
#pragma unroll
    for (int i = 0; i < 16; ++i) bufA[i] = pkv[(size_t)(255 - i) * 256];

    for (int pp = 0; pp < 8; ++pp) {
        const int tA = 240 - 32 * pp;
        const int tB = tA - 16;
#pragma unroll
        for (int i = 0; i < 16; ++i) bufB[i] = pkv[(size_t)(tB + 15 - i) * 256];
        tile_step(bufA, tA, pm, wm, ql, kc, vc, pc,
                  E0, E1, E2, E3, E4, o, Ptile[wv], sbuf[wv], lane, tl, qq);
        if (pp < 7) {
#pragma unroll
            for (int i = 0; i < 16; ++i)
                bufA[i] = pkv[(size_t)(tB - 16 + 15 - i) * 256];
        }
        tile_step(bufB, tB, pm, wm, ql, kc, vc, pc,
                  E0, E1, E2, E3, E4, o, Ptile[wv], sbuf[wv], lane, tl, qq);
    }

    // ---- fused RMSNorm over DV (per head = per wave)
    const float ms = wred(o * o) * (1.0f / 64.0f);
    onorm[j] = o * rsqrtf(ms + EPSf) * norm_w[lane];
    __syncthreads();

    // ---- fused output projection: out[n,j] = onorm . W_o[:,j]
    float acc = 0.f;
#pragma unroll 8
    for (int k = 0; k < Dd; ++k)
        acc = fmaf(onorm[k], W_o[(size_t)k * Dd + j], acc);
    out[(size_t)n * Dd + j] = acc;
}

// ---------------------------------------------------------------------------
extern "C" void kernel_launch(void* const* d_in, const int* in_sizes, int n_in,
                              void* d_out, int out_size, void* d_ws, size_t ws_size,
                              hipStream_t stream)
{
    const float* query    = (const float*)d_in[0];   // (8,64,256)
    const float* keyval   = (const float*)d_in[1];   // (8,256,256)
    const int*   mask     = (const int*)  d_in[2];   // (8,256)
    const float* W_cond   = (const float*)d_in[3];   // (256,256)
    const float* W_q      = (const float*)d_in[4];   // (256,256)
    const float* W_k      = (const float*)d_in[5];   // (256,256)
    const float* W_v      = (const float*)d_in[6];   // (256,256)
    const float* W_gk1    = (const float*)d_in[7];   // (256,16)
    const float* W_gk2    = (const float*)d_in[8];   // (16,256)
    const float* b_gk2    = (const float*)d_in[9];   // (256,)
    const float* W_router = (const float*)d_in[10];  // (256,4)
    const float* norm_w   = (const float*)d_in[11];  // (64,)
    const float* W_o      = (const float*)d_in[12];  // (256,256)

    float* out    = (float*)d_out;        // (8,64,256) = 131072
    float* logits = out + Nn * Dd;        // (N*K, 4)   = 524288

    // workspace layout (floats; all region sizes multiples of 4)
    float* p = (float*)d_ws;
    float* Wb   = p; p += Dd * WB;            // 278528
    float* KVi  = p; p += (size_t)Bb * Kk * 1024;  // 2097152 {k,v,pre,pad}
    float* KVr  = p; p += Bb * Kk * 4;        // 8192
    float* cond = p; p += Nn * Dd;            // 131072
    float* Cbi  = p; p += (size_t)Nn * 1024;  // 524288 {q,k,v,pre}
    float* Cr   = p; p += Nn * 4;             // 2048
    float* KVq8 = p; p += Bb * Dd;            // 2048

    // 1) pack fused weight matrix (includes Wg = W_gk1 @ W_gk2)
    pack_wb<<<(Dd * WB) / 256, dim3(256), 0, stream>>>(
        W_q, W_k, W_v, W_gk1, W_gk2, W_router, Wb);

    // 2) KV projections (no q-region) + cond + keyval_last@W_q, one launch
    gemm1<<<225, dim3(256), 0, stream>>>(
        keyval, query, Wb, W_cond, KVi, KVr, cond, KVq8);

    // 3) Cbi = cond @ Wb (512 x 1088), interleaved
    gemm2<<<68, dim3(256), 0, stream>>>(cond, Wb, Cbi, Cr);

    // 4) router + recurrence + RMSNorm + output projection
    mom_fused<<<Nn, dim3(256), 0, stream>>>(
        (const float4*)KVi, KVr, (const float4*)Cbi, Cr,
        KVq8, b_gk2, mask, W_o, norm_w, out, logits);
}